// Round 1
// baseline (42.744 us; speedup 1.0000x reference)
//
#include <hip/hip_runtime.h>

// LIF neuron recurrence:
//   mem = 0.5*mem + x_t; s = (mem > 1.0); mem *= (1 - s)
// Input  [B=32, T=8, C=128, H=32, W=32] fp32
// Output [B=32, T=8, C=128, H=32, W=32] fp32 spikes
// Per-neuron (b,c,h,w) the scan is sequential in T; neurons are independent.
// Each thread owns 4 consecutive W elements (float4) of one neuron group and
// walks T in registers. Time-stride between samples = C*H*W = 131072 floats,
// but within a time slice consecutive threads are fully coalesced.

constexpr int T_STEPS = 8;
constexpr int CHW4    = 128 * 32 * 32 / 4;   // 32768 float4 per (b,t) slice
constexpr int B       = 32;

__global__ __launch_bounds__(256)
void lif_kernel(const float4* __restrict__ x, float4* __restrict__ out) {
    const int idx = blockIdx.x * blockDim.x + threadIdx.x;  // [0, B*CHW4)
    const int b = idx >> 15;             // idx / CHW4  (CHW4 = 2^15)
    const int i = idx & (CHW4 - 1);      // idx % CHW4
    const long long base = (long long)b * T_STEPS * CHW4 + i;
    const float4* xb = x + base;
    float4* ob = out + base;

    float4 mem = make_float4(0.f, 0.f, 0.f, 0.f);
    #pragma unroll
    for (int t = 0; t < T_STEPS; ++t) {
        const float4 xv = xb[(long long)t * CHW4];
        float4 s;
        float m;
        m = 0.5f * mem.x + xv.x;  s.x = (m > 1.0f) ? 1.f : 0.f;  mem.x = m - m * s.x;
        m = 0.5f * mem.y + xv.y;  s.y = (m > 1.0f) ? 1.f : 0.f;  mem.y = m - m * s.y;
        m = 0.5f * mem.z + xv.z;  s.z = (m > 1.0f) ? 1.f : 0.f;  mem.z = m - m * s.z;
        m = 0.5f * mem.w + xv.w;  s.w = (m > 1.0f) ? 1.f : 0.f;  mem.w = m - m * s.w;
        ob[(long long)t * CHW4] = s;
    }
}

extern "C" void kernel_launch(void* const* d_in, const int* in_sizes, int n_in,
                              void* d_out, int out_size, void* d_ws, size_t ws_size,
                              hipStream_t stream) {
    const float4* x = (const float4*)d_in[0];
    float4* out = (float4*)d_out;
    const int total_vec = B * CHW4;              // 1,048,576 threads
    const int block = 256;
    const int grid = total_vec / block;          // 4096
    lif_kernel<<<grid, block, 0, stream>>>(x, out);
}